// Round 17
// baseline (172.516 us; speedup 1.0000x reference)
//
#include <hip/hip_runtime.h>
#include <hip/hip_bf16.h>
#include <stdint.h>

// Problem constants
#define D_MODEL 1024
#define NHEADS  16
#define DKH     64
#define BATCH   4
#define SEQ     2048
#define NTOK    (BATCH * SEQ)   // 8192

typedef unsigned short u16;
using bf16x8 = __attribute__((ext_vector_type(8))) short;   // 8 bf16 = 4 VGPR (MFMA A/B frag)
using f32x4  = __attribute__((ext_vector_type(4))) float;   // 16x16 MFMA C/D frag
using f32x16 = __attribute__((ext_vector_type(16))) float;  // 32x32 MFMA C/D frag
using u32x2  = __attribute__((ext_vector_type(2))) unsigned int;

// async global->LDS, 16B per lane; LDS dest is wave-uniform base (+lane*16 by HW)
#define GLD16(g, l)                                                            \
  __builtin_amdgcn_global_load_lds(                                            \
      (const __attribute__((address_space(1))) void*)(g),                      \
      (__attribute__((address_space(3))) void*)(l), 16, 0, 0)

__device__ inline u16 f2bf(float f) {
  __hip_bfloat16 h = __float2bfloat16(f);
  return __builtin_bit_cast(u16, h);
}

// single v_exp_f32 via intrinsic (compiler inserts TRANS-op hazard nops)
__device__ inline float fexp2(float x) { return __builtin_amdgcn_exp2f(x); }

// fmaxf triple -> v_max3_f32 (T17; clang fuses nested fmaxf)
__device__ inline float fmax3(float a, float b, float c) { return fmaxf(fmaxf(a, b), c); }

// packed f32x2 -> bf16x2 (RNE in HW); plain VALU op, T12 recipe (m214v22)
__device__ inline unsigned cvtpk(float lo, float hi) {
  unsigned r;
  asm("v_cvt_pk_bf16_f32 %0, %1, %2" : "=v"(r) : "v"(lo), "v"(hi));
  return r;
}

// Build PV B-frag for one K=16 window from 8 in-register P values (T12)
template <int B>
__device__ inline bf16x8 make_pfrag(const f32x16& sv) {
  unsigned x1 = cvtpk(sv[B + 0], sv[B + 1]);
  unsigned y1 = cvtpk(sv[B + 4], sv[B + 5]);
  unsigned x2 = cvtpk(sv[B + 2], sv[B + 3]);
  unsigned y2 = cvtpk(sv[B + 6], sv[B + 7]);
  u32x2 s1 = __builtin_amdgcn_permlane32_swap(x1, y1, false, false);
  u32x2 s2 = __builtin_amdgcn_permlane32_swap(x2, y2, false, false);
  union { unsigned u[4]; bf16x8 v; } r;
  r.u[0] = s1[0]; r.u[1] = s2[0]; r.u[2] = s1[1]; r.u[3] = s2[1];
  return r.v;
}

// ---------------------------------------------------------------- fused converts
__global__ __launch_bounds__(256) void cvt_all(const float* __restrict__ x,
                                               const float* __restrict__ wq,
                                               const float* __restrict__ wk,
                                               const float* __restrict__ wv,
                                               const float* __restrict__ wo,
                                               u16* xb, u16* wqb, u16* wkb, u16* wvb, u16* wob) {
  const int XC = NTOK * D_MODEL / 4;      // 2097152
  const int WC = D_MODEL * D_MODEL / 4;   // 262144
  const int total = XC + 4 * WC;
  for (int i = blockIdx.x * 256 + threadIdx.x; i < total; i += gridDim.x * 256) {
    const float4* s; ushort4* d; int j;
    if (i < XC)              { s = (const float4*)x;  d = (ushort4*)xb;  j = i; }
    else if (i < XC + WC)    { s = (const float4*)wq; d = (ushort4*)wqb; j = i - XC; }
    else if (i < XC + 2*WC)  { s = (const float4*)wk; d = (ushort4*)wkb; j = i - XC - WC; }
    else if (i < XC + 3*WC)  { s = (const float4*)wv; d = (ushort4*)wvb; j = i - XC - 2*WC; }
    else                     { s = (const float4*)wo; d = (ushort4*)wob; j = i - XC - 3*WC; }
    float4 v = s[j];
    d[j] = make_ushort4(f2bf(v.x), f2bf(v.y), f2bf(v.z), f2bf(v.w));
  }
}

// ---------------------------------------------------------------- fused QKV projection
// A [NTOK,D] bf16; Bq/Bk/Bv [D,D] bf16 (nn.Linear layout, C = A*B^T).
// R17: SINGLE-BUFFER 32KB m97/m103 structure (stage->barrier->compute->barrier):
// 5 blocks/CU (vs dbuf 64KB = 2) -- implicit cross-block wave overlap (m114) provides
// the pipelining; m103 measured 912 TF with this structure. T1 XCD swizzle + T2 LDS
// XOR-swizzle retained. z=0: Q out, scaled 0.125*log2(e). z=1: K. z=2: V transposed.
__global__ __launch_bounds__(256) void gemm_qkv(const u16* __restrict__ A,
                                                const u16* __restrict__ Bq,
                                                const u16* __restrict__ Bk,
                                                const u16* __restrict__ Bv,
                                                u16* __restrict__ Qo,
                                                u16* __restrict__ Ko,
                                                u16* __restrict__ Vo) {
  __shared__ u16 As[128 * 64];   // 16 KB
  __shared__ u16 Bs[128 * 64];   // 16 KB -> 32 KB total, 5 blocks/CU
  const int h = blockIdx.x;
  const int L = (h & 7) * 192 + (h >> 3);   // bijective XCD-chunk swizzle (nwg=1536)
  const int z = L / 512;
  const int rr = L % 512;
  const int bM = (rr >> 3) * 128;
  const int bN = (rr & 7) * 128;
  const u16* __restrict__ Bp = z == 0 ? Bq : (z == 1 ? Bk : Bv);
  const int t = threadIdx.x, lane = t & 63, wave = t >> 6;
  const int wr = wave >> 1, wc = wave & 1;
  const int frow = lane & 15, g = lane >> 4;

  f32x4 acc[4][4] = {};

  for (int k0 = 0; k0 < D_MODEL; k0 += 64) {
    __syncthreads();   // prev compute done before overwrite
#pragma unroll
    for (int p = 0; p < 4; ++p) {
      int chunk = p * 256 + t;
      int r = chunk >> 3, cc = chunk & 7;
      int cs = cc ^ (r & 7);   // pre-swizzled source; LDS linear (T2 via rule #21)
      GLD16(A + (size_t)(bM + r) * D_MODEL + k0 + cs * 8, As + (size_t)(p * 256 + (t & ~63)) * 8);
      GLD16(Bp + (size_t)(bN + r) * D_MODEL + k0 + cs * 8, Bs + (size_t)(p * 256 + (t & ~63)) * 8);
    }
    __syncthreads();   // staging visible (barrier drains vmcnt)

    bf16x8 a[2][4], b[2][4];
#pragma unroll
    for (int kk = 0; kk < 2; ++kk) {
#pragma unroll
      for (int m = 0; m < 4; ++m)
        a[kk][m] = *(const bf16x8*)&As[(wr * 64 + m * 16 + frow) * 64 +
                                      (((kk * 4 + g) ^ (frow & 7)) * 8)];
#pragma unroll
      for (int n = 0; n < 4; ++n)
        b[kk][n] = *(const bf16x8*)&Bs[(wc * 64 + n * 16 + frow) * 64 +
                                      (((kk * 4 + g) ^ (frow & 7)) * 8)];
    }
#pragma unroll
    for (int kk = 0; kk < 2; ++kk)
#pragma unroll
      for (int m = 0; m < 4; ++m)
#pragma unroll
        for (int n = 0; n < 4; ++n)
          acc[m][n] = __builtin_amdgcn_mfma_f32_16x16x32_bf16(a[kk][m], b[kk][n], acc[m][n], 0, 0, 0);
  }

  const int r0 = bM + wr * 64 + (lane >> 4) * 4;
  const int c0 = bN + wc * 64 + (lane & 15);
  if (z == 2) {
#pragma unroll
    for (int m = 0; m < 4; ++m)
#pragma unroll
      for (int n = 0; n < 4; ++n) {
        int r = r0 + m * 16;   // token (4-aligned, j stays in one batch)
        int cc = c0 + n * 16;  // d_model col
        size_t off = ((size_t)(r >> 11) * D_MODEL + cc) * SEQ + (r & (SEQ - 1));
        *(ushort4*)(Vo + off) = make_ushort4(f2bf(acc[m][n][0]), f2bf(acc[m][n][1]),
                                             f2bf(acc[m][n][2]), f2bf(acc[m][n][3]));
      }
  } else {
    u16* C = z ? Ko : Qo;
    const float sc = z ? 1.0f : 0.18033688f;  // (1/8)*log2(e): softmax in exp2 domain
#pragma unroll
    for (int m = 0; m < 4; ++m)
#pragma unroll
      for (int n = 0; n < 4; ++n)
#pragma unroll
        for (int j = 0; j < 4; ++j)
          C[(size_t)(r0 + m * 16 + j) * D_MODEL + (c0 + n * 16)] = f2bf(acc[m][n][j] * sc);
  }
}

// ---------------------------------------------------------------- output projection C = A*B^T, f32 out
// R17: single-buffer 32KB structure (same as gemm_qkv) + T1 + T2.
__global__ __launch_bounds__(256) void gemm_out(const u16* __restrict__ A,
                                                const u16* __restrict__ B,
                                                float* __restrict__ C) {
  __shared__ u16 As[128 * 64];
  __shared__ u16 Bs[128 * 64];
  const int h = blockIdx.x;
  const int L = (h & 7) * 64 + (h >> 3);    // bijective XCD-chunk swizzle (nwg=512)
  const int bM = (L >> 3) * 128;
  const int bN = (L & 7) * 128;
  const int t = threadIdx.x, lane = t & 63, wave = t >> 6;
  const int wr = wave >> 1, wc = wave & 1;
  const int frow = lane & 15, g = lane >> 4;

  f32x4 acc[4][4] = {};

  for (int k0 = 0; k0 < D_MODEL; k0 += 64) {
    __syncthreads();
#pragma unroll
    for (int p = 0; p < 4; ++p) {
      int chunk = p * 256 + t;
      int r = chunk >> 3, cc = chunk & 7;
      int cs = cc ^ (r & 7);   // pre-swizzled source; LDS linear
      GLD16(A + (size_t)(bM + r) * D_MODEL + k0 + cs * 8, As + (size_t)(p * 256 + (t & ~63)) * 8);
      GLD16(B + (size_t)(bN + r) * D_MODEL + k0 + cs * 8, Bs + (size_t)(p * 256 + (t & ~63)) * 8);
    }
    __syncthreads();

    bf16x8 a[2][4], b[2][4];
#pragma unroll
    for (int kk = 0; kk < 2; ++kk) {
#pragma unroll
      for (int m = 0; m < 4; ++m)
        a[kk][m] = *(const bf16x8*)&As[(wr * 64 + m * 16 + frow) * 64 +
                                      (((kk * 4 + g) ^ (frow & 7)) * 8)];
#pragma unroll
      for (int n = 0; n < 4; ++n)
        b[kk][n] = *(const bf16x8*)&Bs[(wc * 64 + n * 16 + frow) * 64 +
                                      (((kk * 4 + g) ^ (frow & 7)) * 8)];
    }
#pragma unroll
    for (int kk = 0; kk < 2; ++kk)
#pragma unroll
      for (int m = 0; m < 4; ++m)
#pragma unroll
        for (int n = 0; n < 4; ++n)
          acc[m][n] = __builtin_amdgcn_mfma_f32_16x16x32_bf16(a[kk][m], b[kk][n], acc[m][n], 0, 0, 0);
  }

  const int r0 = bM + wr * 64 + (lane >> 4) * 4;
  const int c0 = bN + wc * 64 + (lane & 15);
#pragma unroll
  for (int m = 0; m < 4; ++m)
#pragma unroll
    for (int n = 0; n < 4; ++n)
#pragma unroll
      for (int j = 0; j < 4; ++j)
        C[(size_t)(r0 + m * 16 + j) * D_MODEL + (c0 + n * 16)] = acc[m][n][j];
}

// ---------------------------------------------------------------- flash attention (causal)
// R13-proven 32x32-MFMA engine (frozen structure). Only change vs R16: max-reduce via
// explicit v_max3 triples (T17, 31->17 ops). 4 waves x 32 q-rows; swapped QK^T;
// lane-local softmax; in-register P via cvt_pk+permlane32_swap; dbuf staging; defer-max.
__global__ __launch_bounds__(256) void attn_fwd(const u16* __restrict__ Q,
                                                const u16* __restrict__ K,
                                                const u16* __restrict__ Vt,
                                                u16* __restrict__ O) {
  __shared__ u16 Kl[2][64 * 64];   // 16 KB (dbuf)
  __shared__ u16 Vl[2][64 * 64];   // 16 KB (dbuf) -> 32 KB total
  const int t = threadIdx.x, lane = t & 63, wave = t >> 6;
  const int q = lane & 31, hi = lane >> 5;
  const int bh = blockIdx.x & 63;           // bh fastest
  const int qtile = 15 - (blockIdx.x >> 6); // heavy-first
  const int q0 = qtile * 128;
  const size_t rowbase = (size_t)(bh >> 4) * SEQ;
  const int hcol = (bh & 15) * DKH;
  const size_t vbase = (size_t)bh * DKH;
  const int qw = q0 + wave * 32;            // this wave's 32 q-rows
  const int nit = qtile * 2 + 2;

  auto stage = [&](int buf, int kv0) {
#pragma unroll
    for (int pp = 0; pp < 2; ++pp) {
      int chunk = pp * 256 + t;
      int r = chunk >> 3, cc = chunk & 7;
      int cs = cc ^ (r & 7);  // pre-swizzled global source; LDS linear
      GLD16(K + (rowbase + kv0 + r) * D_MODEL + hcol + cs * 8,
            &Kl[buf][(size_t)(pp * 256 + (t & ~63)) * 8]);
      GLD16(Vt + (vbase + r) * SEQ + kv0 + cs * 8,
            &Vl[buf][(size_t)(pp * 256 + (t & ~63)) * 8]);
    }
  };

  stage(0, 0);

  // Q B-frags: lane(q,hi) holds Q[qw+q][w*16 + hi*8 + i], w=0..3 (16 VGPR)
  bf16x8 qf[4];
#pragma unroll
  for (int w = 0; w < 4; ++w)
    qf[w] = *(const bf16x8*)&Q[(rowbase + qw + q) * D_MODEL + hcol + w * 16 + hi * 8];

  f32x16 ot0 = {}, ot1 = {};        // O^T: col q=lane&31, row d=crow(r,hi) (+32 for ot1)
  float mstate = -__builtin_inff();
  float lstate = 0.f;

  __syncthreads();
  int cur = 0;
  for (int it = 0; it < nit; ++it) {
    const int kv0 = it * 64;
    if (it + 1 < nit) stage(cur ^ 1, kv0 + 64);

    if (kv0 <= qw + 31) {  // wave-uniform causal participation
      // ---- S^T tiles: s0 = K[kv0..kv0+31] Q^T, s1 = K[kv0+32..63] Q^T
      f32x16 s0 = {}, s1 = {};
      __builtin_amdgcn_s_setprio(1);
#pragma unroll
      for (int w = 0; w < 4; ++w) {
        const int rk0 = q, rk1 = 32 + q;   // (32+q)&7 == q&7
        bf16x8 k0 = *(const bf16x8*)&Kl[cur][rk0 * 64 + (((2 * w + hi) ^ (rk0 & 7)) * 8)];
        bf16x8 k1 = *(const bf16x8*)&Kl[cur][rk1 * 64 + (((2 * w + hi) ^ (rk0 & 7)) * 8)];
        s0 = __builtin_amdgcn_mfma_f32_32x32x16_bf16(k0, qf[w], s0, 0, 0, 0);
        s1 = __builtin_amdgcn_mfma_f32_32x32x16_bf16(k1, qf[w], s1, 0, 0, 0);
      }
      __builtin_amdgcn_s_setprio(0);

      // ---- mask (diagonal tiles only): k = kv0 + {0,32} + crow(r,hi); q_g = qw+q
      const int qg = qw + q;
      if (kv0 + 63 > qw) {
#pragma unroll
        for (int r = 0; r < 16; ++r) {
          const int crow = (r & 3) + 8 * (r >> 2) + 4 * hi;
          if (kv0 + crow > qg) s0[r] = -__builtin_inff();
          if (kv0 + 32 + crow > qg) s1[r] = -__builtin_inff();
        }
      }

      // ---- max over 32 vals via v_max3 triples (T17): 16 -> 6 -> 2 -> 1, + half-swap
      float mx[16];
#pragma unroll
      for (int r = 0; r < 16; ++r) mx[r] = fmaxf(s0[r], s1[r]);
      float a0 = fmax3(mx[0], mx[1], mx[2]);
      float a1 = fmax3(mx[3], mx[4], mx[5]);
      float a2 = fmax3(mx[6], mx[7], mx[8]);
      float a3 = fmax3(mx[9], mx[10], mx[11]);
      float a4 = fmax3(mx[12], mx[13], mx[14]);
      float b0 = fmax3(a0, a1, mx[15]);
      float b1 = fmax3(a2, a3, a4);
      float pmax = fmaxf(b0, b1);
      pmax = fmaxf(pmax, __shfl_xor(pmax, 32));

      // defer-max (T13), log2 domain: P bounded by 2^11.54 = e^8
      if (__any(pmax > mstate + 11.5416f)) {
        float mnew = fmaxf(mstate, pmax);
        float al = fexp2(mstate - mnew);  // first tile: exp2(-inf)=0
        mstate = mnew;
        lstate *= al;
#pragma unroll
        for (int r = 0; r < 16; ++r) { ot0[r] *= al; ot1[r] *= al; }
      }
      const float mm = mstate;

      // ---- exp (in place) + tree row-sum
      float sm[16];
#pragma unroll
      for (int r = 0; r < 16; ++r) {
        s0[r] = fexp2(s0[r] - mm);
        s1[r] = fexp2(s1[r] - mm);
        sm[r] = s0[r] + s1[r];
      }
#pragma unroll
      for (int w2 = 8; w2 > 0; w2 >>= 1)
#pragma unroll
        for (int r = 0; r < w2; ++r) sm[r] += sm[r + w2];
      lstate += sm[0] + __shfl_xor(sm[0], 32);

      // ---- P B-frags in-register (16 cvt_pk + 8 permlane32_swap)
      bf16x8 pb0 = make_pfrag<0>(s0);   // k in [kv0+0,16)
      bf16x8 pb1 = make_pfrag<8>(s0);   // [16,32)
      bf16x8 pb2 = make_pfrag<0>(s1);   // [32,48)
      bf16x8 pb3 = make_pfrag<8>(s1);   // [48,64)

      // ---- O^T += Vt P : A=Vt rows d (ot0: d=q, ot1: d=32+q), B=P cols q
      __builtin_amdgcn_s_setprio(1);
#define PV_STEP(KB, PB)                                                                   \
      {                                                                                   \
        bf16x8 v0 = *(const bf16x8*)&Vl[cur][q * 64 + (((2 * (KB) + hi) ^ (q & 7)) * 8)]; \
        bf16x8 v1 = *(const bf16x8*)&Vl[cur][(32 + q) * 64 + (((2 * (KB) + hi) ^ (q & 7)) * 8)]; \
        ot0 = __builtin_amdgcn_mfma_f32_32x32x16_bf16(v0, PB, ot0, 0, 0, 0);              \
        ot1 = __builtin_amdgcn_mfma_f32_32x32x16_bf16(v1, PB, ot1, 0, 0, 0);              \
      }
      PV_STEP(0, pb0)
      PV_STEP(1, pb1)
      PV_STEP(2, pb2)
      PV_STEP(3, pb3)
#undef PV_STEP
      __builtin_amdgcn_s_setprio(0);
    }
    __syncthreads();
    cur ^= 1;
  }

  // ---- epilogue: O[qw+q][hcol+d] = O^T/l; reg r=4g+j -> d = j + 8g + 4hi (+32 for ot1)
  const float inv = 1.0f / lstate;
  u16* orow = &O[(rowbase + qw + q) * D_MODEL + hcol];
#pragma unroll
  for (int g2 = 0; g2 < 4; ++g2) {
    ushort4 a4 = make_ushort4(f2bf(ot0[4 * g2 + 0] * inv), f2bf(ot0[4 * g2 + 1] * inv),
                              f2bf(ot0[4 * g2 + 2] * inv), f2bf(ot0[4 * g2 + 3] * inv));
    *(ushort4*)&orow[8 * g2 + 4 * hi] = a4;
    ushort4 b4 = make_ushort4(f2bf(ot1[4 * g2 + 0] * inv), f2bf(ot1[4 * g2 + 1] * inv),
                              f2bf(ot1[4 * g2 + 2] * inv), f2bf(ot1[4 * g2 + 3] * inv));
    *(ushort4*)&orow[32 + 8 * g2 + 4 * hi] = b4;
  }
}

// ---------------------------------------------------------------- launch
extern "C" void kernel_launch(void* const* d_in, const int* in_sizes, int n_in,
                              void* d_out, int out_size, void* d_ws, size_t ws_size,
                              hipStream_t stream) {
  const float* x  = (const float*)d_in[0];
  const float* Wq = (const float*)d_in[1];
  const float* Wk = (const float*)d_in[2];
  const float* Wv = (const float*)d_in[3];
  const float* Wo = (const float*)d_in[4];
  float* out = (float*)d_out;

  u16* ws  = (u16*)d_ws;
  u16* xb  = ws;
  u16* wqb = xb + (size_t)NTOK * D_MODEL;
  u16* wkb = wqb + (size_t)D_MODEL * D_MODEL;
  u16* wvb = wkb + (size_t)D_MODEL * D_MODEL;
  u16* wob = wvb + (size_t)D_MODEL * D_MODEL;
  u16* Qb  = wob + (size_t)D_MODEL * D_MODEL;
  u16* Kb  = Qb + (size_t)NTOK * D_MODEL;
  u16* Vb  = Kb + (size_t)NTOK * D_MODEL;   // per-head V^T [B*H*64][SEQ]
  u16* Ob  = xb;  // reuse x's bf16 buffer after projections

  cvt_all<<<2048, 256, 0, stream>>>(x, Wq, Wk, Wv, Wo, xb, wqb, wkb, wvb, wob);

  gemm_qkv<<<1536, 256, 0, stream>>>(xb, wqb, wkb, wvb, Qb, Kb, Vb);

  attn_fwd<<<dim3(16 * 64), 256, 0, stream>>>(Qb, Kb, Vb, Ob);

  gemm_out<<<512, 256, 0, stream>>>(Ob, wob, out);
}

// Round 18
// 166.483 us; speedup vs baseline: 1.0362x; 1.0362x over previous
//
#include <hip/hip_runtime.h>
#include <hip/hip_bf16.h>
#include <stdint.h>

// Problem constants
#define D_MODEL 1024
#define NHEADS  16
#define DKH     64
#define BATCH   4
#define SEQ     2048
#define NTOK    (BATCH * SEQ)   // 8192

typedef unsigned short u16;
using bf16x8 = __attribute__((ext_vector_type(8))) short;   // 8 bf16 = 4 VGPR (MFMA A/B frag)
using f32x4  = __attribute__((ext_vector_type(4))) float;   // 16x16 MFMA C/D frag
using f32x16 = __attribute__((ext_vector_type(16))) float;  // 32x32 MFMA C/D frag
using u32x2  = __attribute__((ext_vector_type(2))) unsigned int;

// async global->LDS, 16B per lane; LDS dest is wave-uniform base (+lane*16 by HW)
#define GLD16(g, l)                                                            \
  __builtin_amdgcn_global_load_lds(                                            \
      (const __attribute__((address_space(1))) void*)(g),                      \
      (__attribute__((address_space(3))) void*)(l), 16, 0, 0)

__device__ inline u16 f2bf(float f) {
  __hip_bfloat16 h = __float2bfloat16(f);
  return __builtin_bit_cast(u16, h);
}

// single v_exp_f32 via intrinsic (compiler inserts TRANS-op hazard nops)
__device__ inline float fexp2(float x) { return __builtin_amdgcn_exp2f(x); }

// fmaxf triple -> v_max3_f32 (T17; clang fuses nested fmaxf)
__device__ inline float fmax3(float a, float b, float c) { return fmaxf(fmaxf(a, b), c); }

// packed f32x2 -> bf16x2 (RNE in HW); plain VALU op, T12 recipe (m214v22)
__device__ inline unsigned cvtpk(float lo, float hi) {
  unsigned r;
  asm("v_cvt_pk_bf16_f32 %0, %1, %2" : "=v"(r) : "v"(lo), "v"(hi));
  return r;
}

// Build PV B-frag for one K=16 window from 8 in-register P values (T12)
template <int B>
__device__ inline bf16x8 make_pfrag(const f32x16& sv) {
  unsigned x1 = cvtpk(sv[B + 0], sv[B + 1]);
  unsigned y1 = cvtpk(sv[B + 4], sv[B + 5]);
  unsigned x2 = cvtpk(sv[B + 2], sv[B + 3]);
  unsigned y2 = cvtpk(sv[B + 6], sv[B + 7]);
  u32x2 s1 = __builtin_amdgcn_permlane32_swap(x1, y1, false, false);
  u32x2 s2 = __builtin_amdgcn_permlane32_swap(x2, y2, false, false);
  union { unsigned u[4]; bf16x8 v; } r;
  r.u[0] = s1[0]; r.u[1] = s2[0]; r.u[2] = s1[1]; r.u[3] = s2[1];
  return r.v;
}

// ---------------------------------------------------------------- fused converts
__global__ __launch_bounds__(256) void cvt_all(const float* __restrict__ x,
                                               const float* __restrict__ wq,
                                               const float* __restrict__ wk,
                                               const float* __restrict__ wv,
                                               const float* __restrict__ wo,
                                               u16* xb, u16* wqb, u16* wkb, u16* wvb, u16* wob) {
  const int XC = NTOK * D_MODEL / 4;      // 2097152
  const int WC = D_MODEL * D_MODEL / 4;   // 262144
  const int total = XC + 4 * WC;
  for (int i = blockIdx.x * 256 + threadIdx.x; i < total; i += gridDim.x * 256) {
    const float4* s; ushort4* d; int j;
    if (i < XC)              { s = (const float4*)x;  d = (ushort4*)xb;  j = i; }
    else if (i < XC + WC)    { s = (const float4*)wq; d = (ushort4*)wqb; j = i - XC; }
    else if (i < XC + 2*WC)  { s = (const float4*)wk; d = (ushort4*)wkb; j = i - XC - WC; }
    else if (i < XC + 3*WC)  { s = (const float4*)wv; d = (ushort4*)wvb; j = i - XC - 2*WC; }
    else                     { s = (const float4*)wo; d = (ushort4*)wob; j = i - XC - 3*WC; }
    float4 v = s[j];
    d[j] = make_ushort4(f2bf(v.x), f2bf(v.y), f2bf(v.z), f2bf(v.w));
  }
}

// ---------------------------------------------------------------- fused QKV projection
// A [NTOK,D] bf16; Bq/Bk/Bv [D,D] bf16 (nn.Linear layout, C = A*B^T).
// R18 = R13-proven: 2-phase dbuf + T1 XCD-chunk swizzle + T2 LDS XOR-swizzle.
// (R17 single-buffer regressed 62->79us: at K=1024/16 iters the dbuf prefetch is
// real work even at 2 blocks/CU; m103's single-buf regime is shape-conditional.)
// z=0: Q out, scaled 0.125*log2(e). z=1: K. z=2: V transposed per-head.
__global__ __launch_bounds__(256) void gemm_qkv(const u16* __restrict__ A,
                                                const u16* __restrict__ Bq,
                                                const u16* __restrict__ Bk,
                                                const u16* __restrict__ Bv,
                                                u16* __restrict__ Qo,
                                                u16* __restrict__ Ko,
                                                u16* __restrict__ Vo) {
  __shared__ u16 As[2][128 * 64];   // 32 KB
  __shared__ u16 Bs[2][128 * 64];   // 32 KB -> 64 KB total, 2 blocks/CU
  const int h = blockIdx.x;
  const int L = (h & 7) * 192 + (h >> 3);   // bijective XCD-chunk swizzle (nwg=1536)
  const int z = L / 512;
  const int rr = L % 512;
  const int bM = (rr >> 3) * 128;
  const int bN = (rr & 7) * 128;
  const u16* __restrict__ Bp = z == 0 ? Bq : (z == 1 ? Bk : Bv);
  const int t = threadIdx.x, lane = t & 63, wave = t >> 6;
  const int wr = wave >> 1, wc = wave & 1;
  const int frow = lane & 15, g = lane >> 4;

  auto stage = [&](int buf, int k0) {
#pragma unroll
    for (int p = 0; p < 4; ++p) {
      int chunk = p * 256 + t;
      int r = chunk >> 3, cc = chunk & 7;
      int cs = cc ^ (r & 7);   // pre-swizzled source; LDS linear (T2 via rule #21)
      GLD16(A + (size_t)(bM + r) * D_MODEL + k0 + cs * 8, &As[buf][(size_t)(p * 256 + (t & ~63)) * 8]);
      GLD16(Bp + (size_t)(bN + r) * D_MODEL + k0 + cs * 8, &Bs[buf][(size_t)(p * 256 + (t & ~63)) * 8]);
    }
  };

  f32x4 acc[4][4] = {};
  stage(0, 0);
  __syncthreads();   // buf0 staged (barrier drains vmcnt)

  int cur = 0;
  for (int k0 = 0; k0 < D_MODEL; k0 += 64) {
    if (k0 + 64 < D_MODEL) stage(cur ^ 1, k0 + 64);   // prefetch overlaps compute

    bf16x8 a[2][4], b[2][4];
#pragma unroll
    for (int kk = 0; kk < 2; ++kk) {
#pragma unroll
      for (int m = 0; m < 4; ++m)
        a[kk][m] = *(const bf16x8*)&As[cur][(wr * 64 + m * 16 + frow) * 64 +
                                           (((kk * 4 + g) ^ (frow & 7)) * 8)];
#pragma unroll
      for (int n = 0; n < 4; ++n)
        b[kk][n] = *(const bf16x8*)&Bs[cur][(wc * 64 + n * 16 + frow) * 64 +
                                           (((kk * 4 + g) ^ (frow & 7)) * 8)];
    }
#pragma unroll
    for (int kk = 0; kk < 2; ++kk)
#pragma unroll
      for (int m = 0; m < 4; ++m)
#pragma unroll
        for (int n = 0; n < 4; ++n)
          acc[m][n] = __builtin_amdgcn_mfma_f32_16x16x32_bf16(a[kk][m], b[kk][n], acc[m][n], 0, 0, 0);

    __syncthreads();  // all waves done with cur; prefetch into cur^1 landed
    cur ^= 1;
  }

  const int r0 = bM + wr * 64 + (lane >> 4) * 4;
  const int c0 = bN + wc * 64 + (lane & 15);
  if (z == 2) {
#pragma unroll
    for (int m = 0; m < 4; ++m)
#pragma unroll
      for (int n = 0; n < 4; ++n) {
        int r = r0 + m * 16;   // token (4-aligned, j stays in one batch)
        int cc = c0 + n * 16;  // d_model col
        size_t off = ((size_t)(r >> 11) * D_MODEL + cc) * SEQ + (r & (SEQ - 1));
        *(ushort4*)(Vo + off) = make_ushort4(f2bf(acc[m][n][0]), f2bf(acc[m][n][1]),
                                             f2bf(acc[m][n][2]), f2bf(acc[m][n][3]));
      }
  } else {
    u16* C = z ? Ko : Qo;
    const float sc = z ? 1.0f : 0.18033688f;  // (1/8)*log2(e): softmax in exp2 domain
#pragma unroll
    for (int m = 0; m < 4; ++m)
#pragma unroll
      for (int n = 0; n < 4; ++n)
#pragma unroll
        for (int j = 0; j < 4; ++j)
          C[(size_t)(r0 + m * 16 + j) * D_MODEL + (c0 + n * 16)] = f2bf(acc[m][n][j] * sc);
  }
}

// ---------------------------------------------------------------- output projection C = A*B^T, f32 out
// R18 = R13-proven: 2-phase dbuf + T1 XCD swizzle + T2 LDS XOR-swizzle.
__global__ __launch_bounds__(256) void gemm_out(const u16* __restrict__ A,
                                                const u16* __restrict__ B,
                                                float* __restrict__ C) {
  __shared__ u16 As[2][128 * 64];
  __shared__ u16 Bs[2][128 * 64];
  const int h = blockIdx.x;
  const int L = (h & 7) * 64 + (h >> 3);    // bijective XCD-chunk swizzle (nwg=512)
  const int bM = (L >> 3) * 128;
  const int bN = (L & 7) * 128;
  const int t = threadIdx.x, lane = t & 63, wave = t >> 6;
  const int wr = wave >> 1, wc = wave & 1;
  const int frow = lane & 15, g = lane >> 4;

  auto stage = [&](int buf, int k0) {
#pragma unroll
    for (int p = 0; p < 4; ++p) {
      int chunk = p * 256 + t;
      int r = chunk >> 3, cc = chunk & 7;
      int cs = cc ^ (r & 7);   // pre-swizzled source; LDS linear
      GLD16(A + (size_t)(bM + r) * D_MODEL + k0 + cs * 8, &As[buf][(size_t)(p * 256 + (t & ~63)) * 8]);
      GLD16(B + (size_t)(bN + r) * D_MODEL + k0 + cs * 8, &Bs[buf][(size_t)(p * 256 + (t & ~63)) * 8]);
    }
  };

  f32x4 acc[4][4] = {};
  stage(0, 0);
  __syncthreads();

  int cur = 0;
  for (int k0 = 0; k0 < D_MODEL; k0 += 64) {
    if (k0 + 64 < D_MODEL) stage(cur ^ 1, k0 + 64);

    bf16x8 a[2][4], b[2][4];
#pragma unroll
    for (int kk = 0; kk < 2; ++kk) {
#pragma unroll
      for (int m = 0; m < 4; ++m)
        a[kk][m] = *(const bf16x8*)&As[cur][(wr * 64 + m * 16 + frow) * 64 +
                                           (((kk * 4 + g) ^ (frow & 7)) * 8)];
#pragma unroll
      for (int n = 0; n < 4; ++n)
        b[kk][n] = *(const bf16x8*)&Bs[cur][(wc * 64 + n * 16 + frow) * 64 +
                                           (((kk * 4 + g) ^ (frow & 7)) * 8)];
    }
#pragma unroll
    for (int kk = 0; kk < 2; ++kk)
#pragma unroll
      for (int m = 0; m < 4; ++m)
#pragma unroll
        for (int n = 0; n < 4; ++n)
          acc[m][n] = __builtin_amdgcn_mfma_f32_16x16x32_bf16(a[kk][m], b[kk][n], acc[m][n], 0, 0, 0);

    __syncthreads();
    cur ^= 1;
  }

  const int r0 = bM + wr * 64 + (lane >> 4) * 4;
  const int c0 = bN + wc * 64 + (lane & 15);
#pragma unroll
  for (int m = 0; m < 4; ++m)
#pragma unroll
    for (int n = 0; n < 4; ++n)
#pragma unroll
      for (int j = 0; j < 4; ++j)
        C[(size_t)(r0 + m * 16 + j) * D_MODEL + (c0 + n * 16)] = acc[m][n][j];
}

// ---------------------------------------------------------------- flash attention (causal)
// R13-proven 32x32-MFMA engine (frozen). 4 waves x 32 q-rows; swapped QK^T; lane-local
// softmax (max3 triples + tree sum); in-register P via cvt_pk+permlane32_swap (T12);
// O^T=mfma32(Vt,P); dbuf XOR-swizzled staging; defer-max; heavy-first grid.
__global__ __launch_bounds__(256) void attn_fwd(const u16* __restrict__ Q,
                                                const u16* __restrict__ K,
                                                const u16* __restrict__ Vt,
                                                u16* __restrict__ O) {
  __shared__ u16 Kl[2][64 * 64];   // 16 KB (dbuf)
  __shared__ u16 Vl[2][64 * 64];   // 16 KB (dbuf) -> 32 KB total
  const int t = threadIdx.x, lane = t & 63, wave = t >> 6;
  const int q = lane & 31, hi = lane >> 5;
  const int bh = blockIdx.x & 63;           // bh fastest
  const int qtile = 15 - (blockIdx.x >> 6); // heavy-first
  const int q0 = qtile * 128;
  const size_t rowbase = (size_t)(bh >> 4) * SEQ;
  const int hcol = (bh & 15) * DKH;
  const size_t vbase = (size_t)bh * DKH;
  const int qw = q0 + wave * 32;            // this wave's 32 q-rows
  const int nit = qtile * 2 + 2;

  auto stage = [&](int buf, int kv0) {
#pragma unroll
    for (int pp = 0; pp < 2; ++pp) {
      int chunk = pp * 256 + t;
      int r = chunk >> 3, cc = chunk & 7;
      int cs = cc ^ (r & 7);  // pre-swizzled global source; LDS linear
      GLD16(K + (rowbase + kv0 + r) * D_MODEL + hcol + cs * 8,
            &Kl[buf][(size_t)(pp * 256 + (t & ~63)) * 8]);
      GLD16(Vt + (vbase + r) * SEQ + kv0 + cs * 8,
            &Vl[buf][(size_t)(pp * 256 + (t & ~63)) * 8]);
    }
  };

  stage(0, 0);

  // Q B-frags: lane(q,hi) holds Q[qw+q][w*16 + hi*8 + i], w=0..3 (16 VGPR)
  bf16x8 qf[4];
#pragma unroll
  for (int w = 0; w < 4; ++w)
    qf[w] = *(const bf16x8*)&Q[(rowbase + qw + q) * D_MODEL + hcol + w * 16 + hi * 8];

  f32x16 ot0 = {}, ot1 = {};        // O^T: col q=lane&31, row d=crow(r,hi) (+32 for ot1)
  float mstate = -__builtin_inff();
  float lstate = 0.f;

  __syncthreads();
  int cur = 0;
  for (int it = 0; it < nit; ++it) {
    const int kv0 = it * 64;
    if (it + 1 < nit) stage(cur ^ 1, kv0 + 64);

    if (kv0 <= qw + 31) {  // wave-uniform causal participation
      // ---- S^T tiles: s0 = K[kv0..kv0+31] Q^T, s1 = K[kv0+32..63] Q^T
      f32x16 s0 = {}, s1 = {};
      __builtin_amdgcn_s_setprio(1);
#pragma unroll
      for (int w = 0; w < 4; ++w) {
        const int rk0 = q, rk1 = 32 + q;   // (32+q)&7 == q&7
        bf16x8 k0 = *(const bf16x8*)&Kl[cur][rk0 * 64 + (((2 * w + hi) ^ (rk0 & 7)) * 8)];
        bf16x8 k1 = *(const bf16x8*)&Kl[cur][rk1 * 64 + (((2 * w + hi) ^ (rk0 & 7)) * 8)];
        s0 = __builtin_amdgcn_mfma_f32_32x32x16_bf16(k0, qf[w], s0, 0, 0, 0);
        s1 = __builtin_amdgcn_mfma_f32_32x32x16_bf16(k1, qf[w], s1, 0, 0, 0);
      }
      __builtin_amdgcn_s_setprio(0);

      // ---- mask (diagonal tiles only): k = kv0 + {0,32} + crow(r,hi); q_g = qw+q
      const int qg = qw + q;
      if (kv0 + 63 > qw) {
#pragma unroll
        for (int r = 0; r < 16; ++r) {
          const int crow = (r & 3) + 8 * (r >> 2) + 4 * hi;
          if (kv0 + crow > qg) s0[r] = -__builtin_inff();
          if (kv0 + 32 + crow > qg) s1[r] = -__builtin_inff();
        }
      }

      // ---- max over 32 vals via v_max3 triples (T17): 16 -> 6 -> 2 -> 1, + half-swap
      float mx[16];
#pragma unroll
      for (int r = 0; r < 16; ++r) mx[r] = fmaxf(s0[r], s1[r]);
      float a0 = fmax3(mx[0], mx[1], mx[2]);
      float a1 = fmax3(mx[3], mx[4], mx[5]);
      float a2 = fmax3(mx[6], mx[7], mx[8]);
      float a3 = fmax3(mx[9], mx[10], mx[11]);
      float a4 = fmax3(mx[12], mx[13], mx[14]);
      float b0 = fmax3(a0, a1, mx[15]);
      float b1 = fmax3(a2, a3, a4);
      float pmax = fmaxf(b0, b1);
      pmax = fmaxf(pmax, __shfl_xor(pmax, 32));

      // defer-max (T13), log2 domain: P bounded by 2^11.54 = e^8
      if (__any(pmax > mstate + 11.5416f)) {
        float mnew = fmaxf(mstate, pmax);
        float al = fexp2(mstate - mnew);  // first tile: exp2(-inf)=0
        mstate = mnew;
        lstate *= al;
#pragma unroll
        for (int r = 0; r < 16; ++r) { ot0[r] *= al; ot1[r] *= al; }
      }
      const float mm = mstate;

      // ---- exp (in place) + tree row-sum
      float sm[16];
#pragma unroll
      for (int r = 0; r < 16; ++r) {
        s0[r] = fexp2(s0[r] - mm);
        s1[r] = fexp2(s1[r] - mm);
        sm[r] = s0[r] + s1[r];
      }
#pragma unroll
      for (int w2 = 8; w2 > 0; w2 >>= 1)
#pragma unroll
        for (int r = 0; r < w2; ++r) sm[r] += sm[r + w2];
      lstate += sm[0] + __shfl_xor(sm[0], 32);

      // ---- P B-frags in-register (16 cvt_pk + 8 permlane32_swap)
      bf16x8 pb0 = make_pfrag<0>(s0);   // k in [kv0+0,16)
      bf16x8 pb1 = make_pfrag<8>(s0);   // [16,32)
      bf16x8 pb2 = make_pfrag<0>(s1);   // [32,48)
      bf16x8 pb3 = make_pfrag<8>(s1);   // [48,64)

      // ---- O^T += Vt P : A=Vt rows d (ot0: d=q, ot1: d=32+q), B=P cols q
      __builtin_amdgcn_s_setprio(1);
#define PV_STEP(KB, PB)                                                                   \
      {                                                                                   \
        bf16x8 v0 = *(const bf16x8*)&Vl[cur][q * 64 + (((2 * (KB) + hi) ^ (q & 7)) * 8)]; \
        bf16x8 v1 = *(const bf16x8*)&Vl[cur][(32 + q) * 64 + (((2 * (KB) + hi) ^ (q & 7)) * 8)]; \
        ot0 = __builtin_amdgcn_mfma_f32_32x32x16_bf16(v0, PB, ot0, 0, 0, 0);              \
        ot1 = __builtin_amdgcn_mfma_f32_32x32x16_bf16(v1, PB, ot1, 0, 0, 0);              \
      }
      PV_STEP(0, pb0)
      PV_STEP(1, pb1)
      PV_STEP(2, pb2)
      PV_STEP(3, pb3)
#undef PV_STEP
      __builtin_amdgcn_s_setprio(0);
    }
    __syncthreads();
    cur ^= 1;
  }

  // ---- epilogue: O[qw+q][hcol+d] = O^T/l; reg r=4g+j -> d = j + 8g + 4hi (+32 for ot1)
  const float inv = 1.0f / lstate;
  u16* orow = &O[(rowbase + qw + q) * D_MODEL + hcol];
#pragma unroll
  for (int g2 = 0; g2 < 4; ++g2) {
    ushort4 a4 = make_ushort4(f2bf(ot0[4 * g2 + 0] * inv), f2bf(ot0[4 * g2 + 1] * inv),
                              f2bf(ot0[4 * g2 + 2] * inv), f2bf(ot0[4 * g2 + 3] * inv));
    *(ushort4*)&orow[8 * g2 + 4 * hi] = a4;
    ushort4 b4 = make_ushort4(f2bf(ot1[4 * g2 + 0] * inv), f2bf(ot1[4 * g2 + 1] * inv),
                              f2bf(ot1[4 * g2 + 2] * inv), f2bf(ot1[4 * g2 + 3] * inv));
    *(ushort4*)&orow[32 + 8 * g2 + 4 * hi] = b4;
  }
}

// ---------------------------------------------------------------- launch
extern "C" void kernel_launch(void* const* d_in, const int* in_sizes, int n_in,
                              void* d_out, int out_size, void* d_ws, size_t ws_size,
                              hipStream_t stream) {
  const float* x  = (const float*)d_in[0];
  const float* Wq = (const float*)d_in[1];
  const float* Wk = (const float*)d_in[2];
  const float* Wv = (const float*)d_in[3];
  const float* Wo = (const float*)d_in[4];
  float* out = (float*)d_out;

  u16* ws  = (u16*)d_ws;
  u16* xb  = ws;
  u16* wqb = xb + (size_t)NTOK * D_MODEL;
  u16* wkb = wqb + (size_t)D_MODEL * D_MODEL;
  u16* wvb = wkb + (size_t)D_MODEL * D_MODEL;
  u16* wob = wvb + (size_t)D_MODEL * D_MODEL;
  u16* Qb  = wob + (size_t)D_MODEL * D_MODEL;
  u16* Kb  = Qb + (size_t)NTOK * D_MODEL;
  u16* Vb  = Kb + (size_t)NTOK * D_MODEL;   // per-head V^T [B*H*64][SEQ]
  u16* Ob  = xb;  // reuse x's bf16 buffer after projections

  cvt_all<<<2048, 256, 0, stream>>>(x, Wq, Wk, Wv, Wo, xb, wqb, wkb, wvb, wob);

  gemm_qkv<<<1536, 256, 0, stream>>>(xb, wqb, wkb, wvb, Qb, Kb, Vb);

  attn_fwd<<<dim3(16 * 64), 256, 0, stream>>>(Qb, Kb, Vb, Ob);

  gemm_out<<<512, 256, 0, stream>>>(Ob, wob, out);
}

// Round 19
// 162.893 us; speedup vs baseline: 1.0591x; 1.0220x over previous
//
#include <hip/hip_runtime.h>
#include <hip/hip_bf16.h>
#include <stdint.h>

// Problem constants
#define D_MODEL 1024
#define NHEADS  16
#define DKH     64
#define BATCH   4
#define SEQ     2048
#define NTOK    (BATCH * SEQ)   // 8192

typedef unsigned short u16;
using bf16x8 = __attribute__((ext_vector_type(8))) short;   // 8 bf16 = 4 VGPR (MFMA A/B frag)
using f32x4  = __attribute__((ext_vector_type(4))) float;   // 16x16 MFMA C/D frag
using f32x16 = __attribute__((ext_vector_type(16))) float;  // 32x32 MFMA C/D frag
using u32x2  = __attribute__((ext_vector_type(2))) unsigned int;

// async global->LDS, 16B per lane; LDS dest is wave-uniform base (+lane*16 by HW)
#define GLD16(g, l)                                                            \
  __builtin_amdgcn_global_load_lds(                                            \
      (const __attribute__((address_space(1))) void*)(g),                      \
      (__attribute__((address_space(3))) void*)(l), 16, 0, 0)

__device__ inline u16 f2bf(float f) {
  __hip_bfloat16 h = __float2bfloat16(f);
  return __builtin_bit_cast(u16, h);
}

// single v_exp_f32 via intrinsic (compiler inserts TRANS-op hazard nops)
__device__ inline float fexp2(float x) { return __builtin_amdgcn_exp2f(x); }

// fmaxf triple -> v_max3_f32 (T17; clang fuses nested fmaxf)
__device__ inline float fmax3(float a, float b, float c) { return fmaxf(fmaxf(a, b), c); }

// packed f32x2 -> bf16x2 (RNE in HW); plain VALU op, T12 recipe (m214v22)
__device__ inline unsigned cvtpk(float lo, float hi) {
  unsigned r;
  asm("v_cvt_pk_bf16_f32 %0, %1, %2" : "=v"(r) : "v"(lo), "v"(hi));
  return r;
}

// Build PV B-frag for one K=16 window from 8 in-register P values (T12)
template <int B>
__device__ inline bf16x8 make_pfrag(const f32x16& sv) {
  unsigned x1 = cvtpk(sv[B + 0], sv[B + 1]);
  unsigned y1 = cvtpk(sv[B + 4], sv[B + 5]);
  unsigned x2 = cvtpk(sv[B + 2], sv[B + 3]);
  unsigned y2 = cvtpk(sv[B + 6], sv[B + 7]);
  u32x2 s1 = __builtin_amdgcn_permlane32_swap(x1, y1, false, false);
  u32x2 s2 = __builtin_amdgcn_permlane32_swap(x2, y2, false, false);
  union { unsigned u[4]; bf16x8 v; } r;
  r.u[0] = s1[0]; r.u[1] = s2[0]; r.u[2] = s1[1]; r.u[3] = s2[1];
  return r.v;
}

// ---------------------------------------------------------------- fused converts
__global__ __launch_bounds__(256) void cvt_all(const float* __restrict__ x,
                                               const float* __restrict__ wq,
                                               const float* __restrict__ wk,
                                               const float* __restrict__ wv,
                                               const float* __restrict__ wo,
                                               u16* xb, u16* wqb, u16* wkb, u16* wvb, u16* wob) {
  const int XC = NTOK * D_MODEL / 4;      // 2097152
  const int WC = D_MODEL * D_MODEL / 4;   // 262144
  const int total = XC + 4 * WC;
  for (int i = blockIdx.x * 256 + threadIdx.x; i < total; i += gridDim.x * 256) {
    const float4* s; ushort4* d; int j;
    if (i < XC)              { s = (const float4*)x;  d = (ushort4*)xb;  j = i; }
    else if (i < XC + WC)    { s = (const float4*)wq; d = (ushort4*)wqb; j = i - XC; }
    else if (i < XC + 2*WC)  { s = (const float4*)wk; d = (ushort4*)wkb; j = i - XC - WC; }
    else if (i < XC + 3*WC)  { s = (const float4*)wv; d = (ushort4*)wvb; j = i - XC - 2*WC; }
    else                     { s = (const float4*)wo; d = (ushort4*)wob; j = i - XC - 3*WC; }
    float4 v = s[j];
    d[j] = make_ushort4(f2bf(v.x), f2bf(v.y), f2bf(v.z), f2bf(v.w));
  }
}

// ---------------------------------------------------------------- fused QKV projection
// A [NTOK,D] bf16; Bq/Bk/Bv [D,D] bf16 (nn.Linear layout, C = A*B^T).
// R13-proven: 2-phase dbuf + T1 XCD-chunk swizzle + T2 LDS XOR-swizzle.
// z=0: Q out, scaled 0.125*log2(e). z=1: K. z=2: V transposed per-head.
__global__ __launch_bounds__(256) void gemm_qkv(const u16* __restrict__ A,
                                                const u16* __restrict__ Bq,
                                                const u16* __restrict__ Bk,
                                                const u16* __restrict__ Bv,
                                                u16* __restrict__ Qo,
                                                u16* __restrict__ Ko,
                                                u16* __restrict__ Vo) {
  __shared__ u16 As[2][128 * 64];   // 32 KB
  __shared__ u16 Bs[2][128 * 64];   // 32 KB -> 64 KB total, 2 blocks/CU
  const int h = blockIdx.x;
  const int L = (h & 7) * 192 + (h >> 3);   // bijective XCD-chunk swizzle (nwg=1536)
  const int z = L / 512;
  const int rr = L % 512;
  const int bM = (rr >> 3) * 128;
  const int bN = (rr & 7) * 128;
  const u16* __restrict__ Bp = z == 0 ? Bq : (z == 1 ? Bk : Bv);
  const int t = threadIdx.x, lane = t & 63, wave = t >> 6;
  const int wr = wave >> 1, wc = wave & 1;
  const int frow = lane & 15, g = lane >> 4;

  auto stage = [&](int buf, int k0) {
#pragma unroll
    for (int p = 0; p < 4; ++p) {
      int chunk = p * 256 + t;
      int r = chunk >> 3, cc = chunk & 7;
      int cs = cc ^ (r & 7);   // pre-swizzled source; LDS linear (T2 via rule #21)
      GLD16(A + (size_t)(bM + r) * D_MODEL + k0 + cs * 8, &As[buf][(size_t)(p * 256 + (t & ~63)) * 8]);
      GLD16(Bp + (size_t)(bN + r) * D_MODEL + k0 + cs * 8, &Bs[buf][(size_t)(p * 256 + (t & ~63)) * 8]);
    }
  };

  f32x4 acc[4][4] = {};
  stage(0, 0);
  __syncthreads();   // buf0 staged (barrier drains vmcnt)

  int cur = 0;
  for (int k0 = 0; k0 < D_MODEL; k0 += 64) {
    if (k0 + 64 < D_MODEL) stage(cur ^ 1, k0 + 64);   // prefetch overlaps compute

    bf16x8 a[2][4], b[2][4];
#pragma unroll
    for (int kk = 0; kk < 2; ++kk) {
#pragma unroll
      for (int m = 0; m < 4; ++m)
        a[kk][m] = *(const bf16x8*)&As[cur][(wr * 64 + m * 16 + frow) * 64 +
                                           (((kk * 4 + g) ^ (frow & 7)) * 8)];
#pragma unroll
      for (int n = 0; n < 4; ++n)
        b[kk][n] = *(const bf16x8*)&Bs[cur][(wc * 64 + n * 16 + frow) * 64 +
                                           (((kk * 4 + g) ^ (frow & 7)) * 8)];
    }
#pragma unroll
    for (int kk = 0; kk < 2; ++kk)
#pragma unroll
      for (int m = 0; m < 4; ++m)
#pragma unroll
        for (int n = 0; n < 4; ++n)
          acc[m][n] = __builtin_amdgcn_mfma_f32_16x16x32_bf16(a[kk][m], b[kk][n], acc[m][n], 0, 0, 0);

    __syncthreads();  // all waves done with cur; prefetch into cur^1 landed
    cur ^= 1;
  }

  const int r0 = bM + wr * 64 + (lane >> 4) * 4;
  const int c0 = bN + wc * 64 + (lane & 15);
  if (z == 2) {
#pragma unroll
    for (int m = 0; m < 4; ++m)
#pragma unroll
      for (int n = 0; n < 4; ++n) {
        int r = r0 + m * 16;   // token (4-aligned, j stays in one batch)
        int cc = c0 + n * 16;  // d_model col
        size_t off = ((size_t)(r >> 11) * D_MODEL + cc) * SEQ + (r & (SEQ - 1));
        *(ushort4*)(Vo + off) = make_ushort4(f2bf(acc[m][n][0]), f2bf(acc[m][n][1]),
                                             f2bf(acc[m][n][2]), f2bf(acc[m][n][3]));
      }
  } else {
    u16* C = z ? Ko : Qo;
    const float sc = z ? 1.0f : 0.18033688f;  // (1/8)*log2(e): softmax in exp2 domain
#pragma unroll
    for (int m = 0; m < 4; ++m)
#pragma unroll
      for (int n = 0; n < 4; ++n)
#pragma unroll
        for (int j = 0; j < 4; ++j)
          C[(size_t)(r0 + m * 16 + j) * D_MODEL + (c0 + n * 16)] = f2bf(acc[m][n][j] * sc);
  }
}

// ---------------------------------------------------------------- output projection C = A*B^T, f32 out
// R13-proven: 2-phase dbuf + T1 XCD swizzle + T2 LDS XOR-swizzle.
__global__ __launch_bounds__(256) void gemm_out(const u16* __restrict__ A,
                                                const u16* __restrict__ B,
                                                float* __restrict__ C) {
  __shared__ u16 As[2][128 * 64];
  __shared__ u16 Bs[2][128 * 64];
  const int h = blockIdx.x;
  const int L = (h & 7) * 64 + (h >> 3);    // bijective XCD-chunk swizzle (nwg=512)
  const int bM = (L >> 3) * 128;
  const int bN = (L & 7) * 128;
  const int t = threadIdx.x, lane = t & 63, wave = t >> 6;
  const int wr = wave >> 1, wc = wave & 1;
  const int frow = lane & 15, g = lane >> 4;

  auto stage = [&](int buf, int k0) {
#pragma unroll
    for (int p = 0; p < 4; ++p) {
      int chunk = p * 256 + t;
      int r = chunk >> 3, cc = chunk & 7;
      int cs = cc ^ (r & 7);   // pre-swizzled source; LDS linear
      GLD16(A + (size_t)(bM + r) * D_MODEL + k0 + cs * 8, &As[buf][(size_t)(p * 256 + (t & ~63)) * 8]);
      GLD16(B + (size_t)(bN + r) * D_MODEL + k0 + cs * 8, &Bs[buf][(size_t)(p * 256 + (t & ~63)) * 8]);
    }
  };

  f32x4 acc[4][4] = {};
  stage(0, 0);
  __syncthreads();

  int cur = 0;
  for (int k0 = 0; k0 < D_MODEL; k0 += 64) {
    if (k0 + 64 < D_MODEL) stage(cur ^ 1, k0 + 64);

    bf16x8 a[2][4], b[2][4];
#pragma unroll
    for (int kk = 0; kk < 2; ++kk) {
#pragma unroll
      for (int m = 0; m < 4; ++m)
        a[kk][m] = *(const bf16x8*)&As[cur][(wr * 64 + m * 16 + frow) * 64 +
                                           (((kk * 4 + g) ^ (frow & 7)) * 8)];
#pragma unroll
      for (int n = 0; n < 4; ++n)
        b[kk][n] = *(const bf16x8*)&Bs[cur][(wc * 64 + n * 16 + frow) * 64 +
                                           (((kk * 4 + g) ^ (frow & 7)) * 8)];
    }
#pragma unroll
    for (int kk = 0; kk < 2; ++kk)
#pragma unroll
      for (int m = 0; m < 4; ++m)
#pragma unroll
        for (int n = 0; n < 4; ++n)
          acc[m][n] = __builtin_amdgcn_mfma_f32_16x16x32_bf16(a[kk][m], b[kk][n], acc[m][n], 0, 0, 0);

    __syncthreads();
    cur ^= 1;
  }

  const int r0 = bM + wr * 64 + (lane >> 4) * 4;
  const int c0 = bN + wc * 64 + (lane & 15);
#pragma unroll
  for (int m = 0; m < 4; ++m)
#pragma unroll
    for (int n = 0; n < 4; ++n)
#pragma unroll
      for (int j = 0; j < 4; ++j)
        C[(size_t)(r0 + m * 16 + j) * D_MODEL + (c0 + n * 16)] = acc[m][n][j];
}

// ---------------------------------------------------------------- flash attention (causal)
// R19: 8-WAVE SHARED-KV BLOCKS. Block = contiguous 256-row q-band (qtiles {2T,2T+1})
// of one (b,h); 8 waves x 32 q-rows. One K/V tile staging per iter serves 8 waves
// (vs 4) -> tile-stagings drop ~2x (17.4K -> 9.2K grid-wide) at +6% wave-rounds
// (contiguous band => max 4-iter skew, unlike R4's 16x pairing). Engine unchanged:
// swapped QK^T, lane-local softmax (max3+tree), in-register P (T12), defer-max,
// dbuf XOR-swizzled gload_lds staging. Grid: 8 bands x 64 bh, heavy-first.
__global__ __launch_bounds__(512) void attn_fwd(const u16* __restrict__ Q,
                                                const u16* __restrict__ K,
                                                const u16* __restrict__ Vt,
                                                u16* __restrict__ O) {
  __shared__ u16 Kl[2][64 * 64];   // 16 KB (dbuf)
  __shared__ u16 Vl[2][64 * 64];   // 16 KB (dbuf) -> 32 KB total
  const int t = threadIdx.x, lane = t & 63, wave = t >> 6;   // wave 0..7
  const int q = lane & 31, hi = lane >> 5;
  const int bh = blockIdx.x & 63;           // bh fastest -> same-bh blocks same XCD
  const int T = 7 - (blockIdx.x >> 6);      // heavy-first band index
  const int q0 = T * 256;
  const size_t rowbase = (size_t)(bh >> 4) * SEQ;
  const int hcol = (bh & 15) * DKH;
  const size_t vbase = (size_t)bh * DKH;
  const int qw = q0 + wave * 32;            // this wave's 32 q-rows
  const int nit = 4 * T + 4;                // KV tiles covering the band's causal prefix

  // 512 threads x 1 chunk = full 64x64 tile per array
  auto stage = [&](int buf, int kv0) {
    int r = t >> 3, cc = t & 7;
    int cs = cc ^ (r & 7);  // pre-swizzled global source; LDS linear
    GLD16(K + (rowbase + kv0 + r) * D_MODEL + hcol + cs * 8,
          &Kl[buf][(size_t)(t & ~63) * 8]);
    GLD16(Vt + (vbase + r) * SEQ + kv0 + cs * 8,
          &Vl[buf][(size_t)(t & ~63) * 8]);
  };

  stage(0, 0);

  // Q B-frags: lane(q,hi) holds Q[qw+q][w*16 + hi*8 + i], w=0..3 (16 VGPR)
  bf16x8 qf[4];
#pragma unroll
  for (int w = 0; w < 4; ++w)
    qf[w] = *(const bf16x8*)&Q[(rowbase + qw + q) * D_MODEL + hcol + w * 16 + hi * 8];

  f32x16 ot0 = {}, ot1 = {};        // O^T: col q=lane&31, row d=crow(r,hi) (+32 for ot1)
  float mstate = -__builtin_inff();
  float lstate = 0.f;

  __syncthreads();
  int cur = 0;
  for (int it = 0; it < nit; ++it) {
    const int kv0 = it * 64;
    if (it + 1 < nit) stage(cur ^ 1, kv0 + 64);

    if (kv0 <= qw + 31) {  // wave-uniform causal participation (max 4-iter skew in band)
      // ---- S^T tiles: s0 = K[kv0..kv0+31] Q^T, s1 = K[kv0+32..63] Q^T
      f32x16 s0 = {}, s1 = {};
      __builtin_amdgcn_s_setprio(1);
#pragma unroll
      for (int w = 0; w < 4; ++w) {
        const int rk0 = q, rk1 = 32 + q;   // (32+q)&7 == q&7
        bf16x8 k0 = *(const bf16x8*)&Kl[cur][rk0 * 64 + (((2 * w + hi) ^ (rk0 & 7)) * 8)];
        bf16x8 k1 = *(const bf16x8*)&Kl[cur][rk1 * 64 + (((2 * w + hi) ^ (rk0 & 7)) * 8)];
        s0 = __builtin_amdgcn_mfma_f32_32x32x16_bf16(k0, qf[w], s0, 0, 0, 0);
        s1 = __builtin_amdgcn_mfma_f32_32x32x16_bf16(k1, qf[w], s1, 0, 0, 0);
      }
      __builtin_amdgcn_s_setprio(0);

      // ---- mask (diagonal tiles only): k = kv0 + {0,32} + crow(r,hi); q_g = qw+q
      const int qg = qw + q;
      if (kv0 + 63 > qw) {
#pragma unroll
        for (int r = 0; r < 16; ++r) {
          const int crow = (r & 3) + 8 * (r >> 2) + 4 * hi;
          if (kv0 + crow > qg) s0[r] = -__builtin_inff();
          if (kv0 + 32 + crow > qg) s1[r] = -__builtin_inff();
        }
      }

      // ---- max over 32 vals via v_max3 triples (T17): 16 -> 6 -> 2 -> 1, + half-swap
      float mx[16];
#pragma unroll
      for (int r = 0; r < 16; ++r) mx[r] = fmaxf(s0[r], s1[r]);
      float a0 = fmax3(mx[0], mx[1], mx[2]);
      float a1 = fmax3(mx[3], mx[4], mx[5]);
      float a2 = fmax3(mx[6], mx[7], mx[8]);
      float a3 = fmax3(mx[9], mx[10], mx[11]);
      float a4 = fmax3(mx[12], mx[13], mx[14]);
      float b0 = fmax3(a0, a1, mx[15]);
      float b1 = fmax3(a2, a3, a4);
      float pmax = fmaxf(b0, b1);
      pmax = fmaxf(pmax, __shfl_xor(pmax, 32));

      // defer-max (T13), log2 domain: P bounded by 2^11.54 = e^8
      if (__any(pmax > mstate + 11.5416f)) {
        float mnew = fmaxf(mstate, pmax);
        float al = fexp2(mstate - mnew);  // first tile: exp2(-inf)=0
        mstate = mnew;
        lstate *= al;
#pragma unroll
        for (int r = 0; r < 16; ++r) { ot0[r] *= al; ot1[r] *= al; }
      }
      const float mm = mstate;

      // ---- exp (in place) + tree row-sum
      float sm[16];
#pragma unroll
      for (int r = 0; r < 16; ++r) {
        s0[r] = fexp2(s0[r] - mm);
        s1[r] = fexp2(s1[r] - mm);
        sm[r] = s0[r] + s1[r];
      }
#pragma unroll
      for (int w2 = 8; w2 > 0; w2 >>= 1)
#pragma unroll
        for (int r = 0; r < w2; ++r) sm[r] += sm[r + w2];
      lstate += sm[0] + __shfl_xor(sm[0], 32);

      // ---- P B-frags in-register (16 cvt_pk + 8 permlane32_swap)
      bf16x8 pb0 = make_pfrag<0>(s0);   // k in [kv0+0,16)
      bf16x8 pb1 = make_pfrag<8>(s0);   // [16,32)
      bf16x8 pb2 = make_pfrag<0>(s1);   // [32,48)
      bf16x8 pb3 = make_pfrag<8>(s1);   // [48,64)

      // ---- O^T += Vt P : A=Vt rows d (ot0: d=q, ot1: d=32+q), B=P cols q
      __builtin_amdgcn_s_setprio(1);
#define PV_STEP(KB, PB)                                                                   \
      {                                                                                   \
        bf16x8 v0 = *(const bf16x8*)&Vl[cur][q * 64 + (((2 * (KB) + hi) ^ (q & 7)) * 8)]; \
        bf16x8 v1 = *(const bf16x8*)&Vl[cur][(32 + q) * 64 + (((2 * (KB) + hi) ^ (q & 7)) * 8)]; \
        ot0 = __builtin_amdgcn_mfma_f32_32x32x16_bf16(v0, PB, ot0, 0, 0, 0);              \
        ot1 = __builtin_amdgcn_mfma_f32_32x32x16_bf16(v1, PB, ot1, 0, 0, 0);              \
      }
      PV_STEP(0, pb0)
      PV_STEP(1, pb1)
      PV_STEP(2, pb2)
      PV_STEP(3, pb3)
#undef PV_STEP
      __builtin_amdgcn_s_setprio(0);
    }
    __syncthreads();
    cur ^= 1;
  }

  // ---- epilogue: O[qw+q][hcol+d] = O^T/l; reg r=4g+j -> d = j + 8g + 4hi (+32 for ot1)
  const float inv = 1.0f / lstate;
  u16* orow = &O[(rowbase + qw + q) * D_MODEL + hcol];
#pragma unroll
  for (int g2 = 0; g2 < 4; ++g2) {
    ushort4 a4 = make_ushort4(f2bf(ot0[4 * g2 + 0] * inv), f2bf(ot0[4 * g2 + 1] * inv),
                              f2bf(ot0[4 * g2 + 2] * inv), f2bf(ot0[4 * g2 + 3] * inv));
    *(ushort4*)&orow[8 * g2 + 4 * hi] = a4;
    ushort4 b4 = make_ushort4(f2bf(ot1[4 * g2 + 0] * inv), f2bf(ot1[4 * g2 + 1] * inv),
                              f2bf(ot1[4 * g2 + 2] * inv), f2bf(ot1[4 * g2 + 3] * inv));
    *(ushort4*)&orow[32 + 8 * g2 + 4 * hi] = b4;
  }
}

// ---------------------------------------------------------------- launch
extern "C" void kernel_launch(void* const* d_in, const int* in_sizes, int n_in,
                              void* d_out, int out_size, void* d_ws, size_t ws_size,
                              hipStream_t stream) {
  const float* x  = (const float*)d_in[0];
  const float* Wq = (const float*)d_in[1];
  const float* Wk = (const float*)d_in[2];
  const float* Wv = (const float*)d_in[3];
  const float* Wo = (const float*)d_in[4];
  float* out = (float*)d_out;

  u16* ws  = (u16*)d_ws;
  u16* xb  = ws;
  u16* wqb = xb + (size_t)NTOK * D_MODEL;
  u16* wkb = wqb + (size_t)D_MODEL * D_MODEL;
  u16* wvb = wkb + (size_t)D_MODEL * D_MODEL;
  u16* wob = wvb + (size_t)D_MODEL * D_MODEL;
  u16* Qb  = wob + (size_t)D_MODEL * D_MODEL;
  u16* Kb  = Qb + (size_t)NTOK * D_MODEL;
  u16* Vb  = Kb + (size_t)NTOK * D_MODEL;   // per-head V^T [B*H*64][SEQ]
  u16* Ob  = xb;  // reuse x's bf16 buffer after projections

  cvt_all<<<2048, 256, 0, stream>>>(x, Wq, Wk, Wv, Wo, xb, wqb, wkb, wvb, wob);

  gemm_qkv<<<1536, 256, 0, stream>>>(xb, wqb, wkb, wvb, Qb, Kb, Vb);

  attn_fwd<<<dim3(8 * 64), 512, 0, stream>>>(Qb, Kb, Vb, Ob);

  gemm_out<<<512, 256, 0, stream>>>(Ob, wob, out);
}